// Round 1
// baseline (163.592 us; speedup 1.0000x reference)
//
#include <hip/hip_runtime.h>
#include <math.h>

namespace {

constexpr int kB    = 16384;
constexpr int kS0   = 7;
constexpr int kS1   = 7;
constexpr int kD    = 30;
constexpr int kCells = kB * kS0 * kS1;   // 802816
constexpr int TPB   = 256;
constexpr int CPB   = 256;               // cells per block (1 cell / thread)
constexpr int NBLK  = kCells / CPB;      // 3136 (exact)
constexpr int TILE_F  = CPB * kD;        // 7680 floats staged per block
constexpr int TILE_V4 = TILE_F / 4;      // 1920 float4 loads per block
constexpr int LSTRIDE = kD + 1;          // 31: odd stride -> conflict-free reads
constexpr float kInv7 = 1.0f / 7.0f;
constexpr float kWC = 5.0f;
constexpr float kWN = 0.5f;

__device__ __forceinline__ float frcp(float x) {
    return __builtin_amdgcn_rcpf(x);     // v_rcp_f32, ~1e-7 rel err (2% tol)
}

__device__ __forceinline__ float sigm(float x) {
    return frcp(1.0f + __expf(-x));
}

// r11: coalesced-staging rewrite of the zero-LDS r6/r10 structure.
// Rationale (counters): yolo dispatch was ~2.2x the 18.4us HBM floor. The
// 15x dwordx2-at-120B-stride loads crack each wave instruction into ~60
// cache-line transactions (~900/wave to cover 60 lines, 15x over-crack) --
// TA-serialization comparable to the whole HBM time. Here the pred tile is
// loaded as contiguous dwordx4 (8 cracks/instr, minimal), scattered to LDS
// at a +1-padded stride (31 floats: odd -> 64-lane reads land 2/bank = free;
// scatter writes ~2-3-way ~= free), and compute streams from LDS. Softmax
// streams classes straight from LDS -> no f[30] register array.
__global__ void __launch_bounds__(TPB, 4) yolo_loss_kernel(
    const float* __restrict__ pred,
    const int*   __restrict__ grid,
    const float* __restrict__ tbox,
    const int*   __restrict__ tcls,
    float* __restrict__ partials)   // NBLK f32 in d_ws (all overwritten)
{
    __shared__ float sp[CPB * LSTRIDE];   // 31,744 B  (5 blocks/CU LDS cap)
    __shared__ float wsum[TPB / 64];

    const int tid  = threadIdx.x;
    const int cell = blockIdx.x * CPB + tid;
    const int wave = tid >> 6;
    const int lane = tid & 63;

    // per-cell side loads: stride == width -> fully coalesced; issued first
    // so they resolve under the staging phase.
    const float4 tb4 = reinterpret_cast<const float4*>(tbox)[cell];
    const int g  = grid[cell];
    const int tc = tcls[cell];

    // ---- coalesced staging: 1920 contiguous float4 -> padded LDS tile ----
    const float4* __restrict__ gp4 =
        reinterpret_cast<const float4*>(pred + (size_t)blockIdx.x * TILE_F);
    #pragma unroll
    for (int k = 0; k < 8; ++k) {
        const int i = tid + k * TPB;
        if (k < 7 || i < TILE_V4) {        // tail: threads 0..127 only
            const float4 v = gp4[i];
            const int L0 = 4 * i;          // linear float idx in tile
            const int c0 = L0 / 30;        // cell of first element (magic mul)
            const int j0 = L0 - 30 * c0;
            // padded addr = L + cell(L); float4 may straddle one cell edge
            sp[L0 + 0 + c0]                      = v.x;   // j0 <= 28, never wraps
            sp[L0 + 1 + c0 + ((j0 + 1) >= 30)]  = v.y;
            sp[L0 + 2 + c0 + ((j0 + 2) >= 30)]  = v.z;
            sp[L0 + 3 + c0 + ((j0 + 3) >= 30)]  = v.w;
        }
    }
    __syncthreads();

    // ---- per-cell compute, streaming from LDS (stride 31, conflict-free) ----
    const float* __restrict__ fb = &sp[tid * LSTRIDE];

    const int cj = cell % kS1;            // column -> xg
    const int ci = (cell / kS1) % kS0;    // row    -> yg
    const float tox = tb4.x, toy = tb4.y, tw = tb4.z, th = tb4.w;

    const float conf0 = sigm(fb[0]);
    const float conf1 = sigm(fb[1]);
    float pbx[2], pby[2], pbw[2], pbh[2];
    #pragma unroll
    for (int k = 0; k < 2; ++k) {
        pbx[k] = sigm(fb[2 + 4 * k + 0]);
        pby[k] = sigm(fb[2 + 4 * k + 1]);
        pbw[k] = sigm(fb[2 + 4 * k + 2]);
        pbh[k] = sigm(fb[2 + 4 * k + 3]);
    }

    // softmax over 20 classes, no max-subtraction (inputs ~N(0,1):
    // exp <= ~e^6, 20-term fp32 sum nowhere near overflow)
    float csum = 0.0f, et = 0.0f;
    #pragma unroll
    for (int q = 0; q < 20; ++q) {
        const float e = __expf(fb[10 + q]);
        csum += e;
        et = (q == tc) ? e : et;          // constant q -> cndmask
    }
    const float cls_t = et * frcp(csum);

    // IOU of both predicted boxes vs target box
    const float x = (float)cj, y = (float)ci;
    const float tcx = (x + tox) * kInv7;
    const float tcy = (y + toy) * kInv7;
    const float thw = tw * 0.5f, thh = th * 0.5f;
    const float tarea = tw * th;

    float iou[2];
    #pragma unroll
    for (int k = 0; k < 2; ++k) {
        const float pcx = (x + pbx[k]) * kInv7;
        const float pcy = (y + pby[k]) * kInv7;
        const float pw = pbw[k], ph = pbh[k];
        const float tb_ = fminf(tcx + thw, pcx + pw * 0.5f) - fmaxf(tcx - thw, pcx - pw * 0.5f);
        const float lr_ = fminf(tcy + thh, pcy + ph * 0.5f) - fmaxf(tcy - thh, pcy - ph * 0.5f);
        float inter = tb_ * lr_;
        inter = (tb_ < 0.0f || lr_ < 0.0f) ? 0.0f : inter;
        iou[k] = inter * frcp(tarea + pw * ph - inter);
    }

    const bool b1 = (iou[1] > iou[0]);     // tie -> box 0 (first-max)
    const float bx = b1 ? pbx[1] : pbx[0];
    const float by = b1 ? pby[1] : pby[0];
    const float bw = b1 ? pbw[1] : pbw[0];
    const float bh = b1 ? pbh[1] : pbh[0];
    const float conf_b = b1 ? conf1 : conf0;
    const float iou_b  = b1 ? iou[1] : iou[0];

    const float dx = bx - tox;
    const float dy = by - toy;
    const float dw = sqrtf(bw) - sqrtf(tw);
    const float dh = sqrtf(bh) - sqrtf(th);
    const float coord = dx * dx + dy * dy + dw * dw + dh * dh;
    const float d1 = conf_b - iou_b;
    const float d2 = 1.0f - cls_t;
    const float obj   = kWC * coord + d1 * d1 + d2 * d2;
    const float noobj = kWN * (conf0 * conf0 + conf1 * conf1);

    float v = (g == 1) ? obj : noobj;

    // wave64 shuffle reduce, cross-wave via tiny LDS, plain store
    #pragma unroll
    for (int off = 32; off > 0; off >>= 1) v += __shfl_down(v, off, 64);
    if (lane == 0) wsum[wave] = v;
    __syncthreads();
    if (tid == 0) {
        partials[blockIdx.x] = wsum[0] + wsum[1] + wsum[2] + wsum[3];
    }
}

__global__ void __launch_bounds__(256) finish_kernel(
    const float* __restrict__ partials, float* __restrict__ out)
{
    __shared__ float wsum[4];
    const int tid = threadIdx.x;
    float v = 0.0f;
    for (int i = tid; i < NBLK; i += 256) v += partials[i];  // 13 iters
    #pragma unroll
    for (int off = 32; off > 0; off >>= 1) v += __shfl_down(v, off, 64);
    if ((tid & 63) == 0) wsum[tid >> 6] = v;
    __syncthreads();
    if (tid == 0) out[0] = (wsum[0] + wsum[1] + wsum[2] + wsum[3]) * (1.0f / kB);
}

} // namespace

extern "C" void kernel_launch(void* const* d_in, const int* in_sizes, int n_in,
                              void* d_out, int out_size, void* d_ws, size_t ws_size,
                              hipStream_t stream) {
    const float* pred = (const float*)d_in[0];
    const int*   grid = (const int*)d_in[1];
    const float* tbox = (const float*)d_in[2];
    const int*   tcls = (const int*)d_in[3];
    float* out      = (float*)d_out;
    float* partials = (float*)d_ws;       // NBLK f32; fully overwritten

    yolo_loss_kernel<<<NBLK, TPB, 0, stream>>>(pred, grid, tbox, tcls, partials);
    finish_kernel<<<1, 256, 0, stream>>>(partials, out);
}